// Round 4
// baseline (230.449 us; speedup 1.0000x reference)
//
#include <hip/hip_runtime.h>

// Sparsemax over rows: B=131072, D=256, fp32.
//
// Persistent-wave version. Grid = 2048 blocks x 256 thr (8 blocks/CU on 256
// CUs = 32 waves/CU, full thread slots, no launch ramp/tail). Each wave owns
// nrows/8192 = 16 rows, one row per step (lane holds 4 contiguous floats),
// with a 1-deep software pipeline: row i+1's load is issued BEFORE row i's
// compute, so HBM latency hides under the compute chain and each wave
// delivers a steady stream of 1-KB loads (fixes the load-arrival-rate limit
// that pinned previous versions at ~31% HBM).
//
// All reductions are DPP-based (VALU pipe only, no ds_swizzle/bpermute):
// row_shr 1/2/4/8 builds per-16-lane inclusive partials (lane 15 of each row
// group = group total), row_bcast:15 + row_bcast:31 combine groups, lane 63
// holds the wave total, readlane(63) broadcasts it through an SGPR (free
// scalar operand for the following compares). ~5-8 cy/hop vs ~64 on the ds
// path: cuts the serial chain ~3x, which is what makes 1-deep prefetch
// sufficient.
//
// tau via Michelot from the tight superset A0 = {z > max-1} (valid since
// tau* in [max-1, max)): ~2-4 iterations on Gaussian rows. Convergence check
// (scalar ballot counts) runs BEFORE the sum reduce, so the final iteration
// costs no reduction. Count equality => active set stable => fixed point.

#define D_COLS 256

typedef float fvec4 __attribute__((ext_vector_type(4)));

// update_dpp(old, src, ctrl, row_mask, bank_mask, bound_ctrl=false):
// invalid source lanes receive `old` (the reduction identity).
#define DPP_MAX(v, ctrl)                                              \
  v = fmaxf(v, __int_as_float(__builtin_amdgcn_update_dpp(            \
                   (int)0xff800000 /* -inf */, __float_as_int(v),     \
                   ctrl, 0xF, 0xF, false)))
#define DPP_ADD(v, ctrl)                                              \
  v = v + __int_as_float(__builtin_amdgcn_update_dpp(                 \
              0 /* +0.0f */, __float_as_int(v), ctrl, 0xF, 0xF, false))

// ctrl encodings: row_shr:1/2/4/8 = 0x111/0x112/0x114/0x118,
// row_bcast:15 = 0x142, row_bcast:31 = 0x143.
#define DPP_REDUCE_MAX(v)                                             \
  do {                                                                \
    DPP_MAX(v, 0x111); DPP_MAX(v, 0x112); DPP_MAX(v, 0x114);          \
    DPP_MAX(v, 0x118); DPP_MAX(v, 0x142); DPP_MAX(v, 0x143);          \
  } while (0)
#define DPP_REDUCE_ADD(v)                                             \
  do {                                                                \
    DPP_ADD(v, 0x111); DPP_ADD(v, 0x112); DPP_ADD(v, 0x114);          \
    DPP_ADD(v, 0x118); DPP_ADD(v, 0x142); DPP_ADD(v, 0x143);          \
  } while (0)

__global__ __launch_bounds__(256) void sparsemax_kernel(
    const float* __restrict__ x, float* __restrict__ out, int nrows) {
  const int lane = threadIdx.x & 63;
  const int wid = blockIdx.x * 4 + (threadIdx.x >> 6);
  const int nw = gridDim.x * 4;  // total waves = rows in flight

  int row = wid;
  if (row >= nrows) return;

  // Prime the pipeline: row's data in flight before the loop body.
  fvec4 vn = ((const fvec4*)(x + (size_t)row * D_COLS))[lane];

  for (; row < nrows; row += nw) {
    fvec4 v = vn;  // waits on the in-flight load
    const int nrow = row + nw;
    if (nrow < nrows)  // wave-uniform; issue next row's load NOW
      vn = ((const fvec4*)(x + (size_t)nrow * D_COLS))[lane];

    // Row max -> initial tau = max - 1 (uniform via readlane/SGPR).
    float m = fmaxf(fmaxf(v.x, v.y), fmaxf(v.z, v.w));
    DPP_REDUCE_MAX(m);
    float tau =
        __int_as_float(__builtin_amdgcn_readlane(__float_as_int(m), 63)) - 1.0f;

    int prev = -1;  // impossible count => no break on first iteration
    for (int it = 0; it < 64; ++it) {
      unsigned long long b0 = __ballot(v.x > tau);
      unsigned long long b1 = __ballot(v.y > tau);
      unsigned long long b2 = __ballot(v.z > tau);
      unsigned long long b3 = __ballot(v.w > tau);
      const int c = __popcll(b0) + __popcll(b1) + __popcll(b2) + __popcll(b3);

      if (c == prev) break;  // active set stable => tau is the fixed point

      float ls = ((v.x > tau) ? v.x : 0.0f) + ((v.y > tau) ? v.y : 0.0f) +
                 ((v.z > tau) ? v.z : 0.0f) + ((v.w > tau) ? v.w : 0.0f);
      DPP_REDUCE_ADD(ls);
      const float lsum =
          __int_as_float(__builtin_amdgcn_readlane(__float_as_int(ls), 63));

      // c is a small exact int: rcp error ~1e-7 rel, far under tolerance;
      // avoids the precise-div fixup sequence in the dependent chain.
      tau = (lsum - 1.0f) * __builtin_amdgcn_rcpf((float)c);
      prev = c;
    }

    fvec4 o;
    o.x = fmaxf(v.x - tau, 0.0f);
    o.y = fmaxf(v.y - tau, 0.0f);
    o.z = fmaxf(v.z - tau, 0.0f);
    o.w = fmaxf(v.w - tau, 0.0f);
    ((fvec4*)(out + (size_t)row * D_COLS))[lane] = o;
  }
}

extern "C" void kernel_launch(void* const* d_in, const int* in_sizes, int n_in,
                              void* d_out, int out_size, void* d_ws, size_t ws_size,
                              hipStream_t stream) {
  const float* x = (const float*)d_in[0];
  float* out = (float*)d_out;
  const int nrows = in_sizes[0] / D_COLS;
  // 8 blocks/CU x 256 CUs: full 32-wave/CU residency, persistent grid-stride.
  int blocks = 2048;
  const int max_blocks = (nrows + 3) / 4;
  if (blocks > max_blocks) blocks = max_blocks;
  sparsemax_kernel<<<blocks, 256, 0, stream>>>(x, out, nrows);
}